// Round 7
// baseline (21785.139 us; speedup 1.0000x reference)
//
#include <hip/hip_runtime.h>
#include <cstdint>
#include <cstddef>

#define T_SEQ 4096
#define HSZ   512
#define NGATE 2048   // 4*HSZ
#define DIN   1024
#define NB0   16     // layer-0 blocks per direction
#define HB0   32     // h-elements per layer-0 block
#define NB1   32     // layer-1 blocks per direction
#define HB1   16     // h-elements per layer-1 block
#define SLOTS 8      // exchange slots (epoch & 7)

typedef unsigned long long u64;
typedef unsigned int u32;

__device__ __forceinline__ u64 exld(const u64* p) {
  return __hip_atomic_load(p, __ATOMIC_RELAXED, __HIP_MEMORY_SCOPE_AGENT);
}
__device__ __forceinline__ void exst(u64* p, u64 v) {
  __hip_atomic_store(p, v, __ATOMIC_RELAXED, __HIP_MEMORY_SCOPE_AGENT);
}
__device__ __forceinline__ int pgld(const u32* p) {
  return (int)__hip_atomic_load(p, __ATOMIC_RELAXED, __HIP_MEMORY_SCOPE_AGENT);
}
__device__ __forceinline__ void pgst(u32* p, u32 v) {
  __hip_atomic_store(p, v, __ATOMIC_RELAXED, __HIP_MEMORY_SCOPE_AGENT);
}

__device__ __forceinline__ float fsigmoid(float x) { return 1.f / (1.f + __expf(-x)); }
__device__ __forceinline__ float ftanh(float x) {
  x = fminf(fmaxf(x, -10.f), 10.f);
  const float e = __expf(2.f * x);
  return (e - 1.f) / (e + 1.f);
}
__device__ __forceinline__ float dot4(float4 a, float4 b) {
  return a.x*b.x + a.y*b.y + a.z*b.z + a.w*b.w;
}

// ---------------- init: zero exchange (epoch0 == 0-valued partials/h) + progress flags ----------------
__global__ void init_sync_kernel(u64* exbase, u32* prog) {
  const size_t NEX = (size_t)2*SLOTS*NB0*NGATE + (size_t)2*SLOTS*NB1*NGATE + (size_t)2*SLOTS*HSZ;
  const size_t tid = (size_t)blockIdx.x * blockDim.x + threadIdx.x;
  for (size_t i = tid; i < NEX; i += (size_t)gridDim.x * blockDim.x) exst(&exbase[i], 0ull);
  if (tid < 2*(NB0+NB1)) pgst(&prog[tid], 0u);
}

// ---------------- fp32 GEMM with bias: P[t,r] = sum_k X[t,k]*W[r,k] + bi[r] + bh[r] ----------------
__global__ __launch_bounds__(256, 2)
void gemm_bias_kernel(const float* __restrict__ Xf, const float* __restrict__ Xb,
                      const float* __restrict__ Wf, const float* __restrict__ Wb,
                      const float* __restrict__ bif, const float* __restrict__ bhf,
                      const float* __restrict__ bib, const float* __restrict__ bhb,
                      float* __restrict__ Pf, float* __restrict__ Pb, int K)
{
  const int dir = blockIdx.z;
  const float* X  = dir ? Xb  : Xf;
  const float* W  = dir ? Wb  : Wf;
  const float* bi = dir ? bib : bif;
  const float* bh = dir ? bhb : bhf;
  float* P        = dir ? Pb  : Pf;

  const int m0 = blockIdx.x * 128;
  const int n0 = blockIdx.y * 128;
  const int tid = threadIdx.x;
  const int lr = tid >> 1;
  const int lk = (tid & 1) * 8;

  __shared__ float As[16*128];
  __shared__ float Bs[16*128];

  float acc[8][8];
  #pragma unroll
  for (int i = 0; i < 8; ++i)
    #pragma unroll
    for (int j = 0; j < 8; ++j) acc[i][j] = 0.f;

  for (int k0 = 0; k0 < K; k0 += 16) {
    const float4 a0 = *(const float4*)(X + (size_t)(m0+lr)*K + k0 + lk);
    const float4 a1 = *(const float4*)(X + (size_t)(m0+lr)*K + k0 + lk + 4);
    const float4 b0 = *(const float4*)(W + (size_t)(n0+lr)*K + k0 + lk);
    const float4 b1 = *(const float4*)(W + (size_t)(n0+lr)*K + k0 + lk + 4);
    __syncthreads();
    As[(lk+0)*128+lr]=a0.x; As[(lk+1)*128+lr]=a0.y; As[(lk+2)*128+lr]=a0.z; As[(lk+3)*128+lr]=a0.w;
    As[(lk+4)*128+lr]=a1.x; As[(lk+5)*128+lr]=a1.y; As[(lk+6)*128+lr]=a1.z; As[(lk+7)*128+lr]=a1.w;
    Bs[(lk+0)*128+lr]=b0.x; Bs[(lk+1)*128+lr]=b0.y; Bs[(lk+2)*128+lr]=b0.z; Bs[(lk+3)*128+lr]=b0.w;
    Bs[(lk+4)*128+lr]=b1.x; Bs[(lk+5)*128+lr]=b1.y; Bs[(lk+6)*128+lr]=b1.z; Bs[(lk+7)*128+lr]=b1.w;
    __syncthreads();
    #pragma unroll
    for (int kk = 0; kk < 16; ++kk) {
      const float4 A0 = *(const float4*)(As + kk*128 + (tid&15)*8);
      const float4 A1 = *(const float4*)(As + kk*128 + (tid&15)*8 + 4);
      const float4 B0 = *(const float4*)(Bs + kk*128 + (tid>>4)*8);
      const float4 B1 = *(const float4*)(Bs + kk*128 + (tid>>4)*8 + 4);
      const float av[8] = {A0.x,A0.y,A0.z,A0.w,A1.x,A1.y,A1.z,A1.w};
      const float bv[8] = {B0.x,B0.y,B0.z,B0.w,B1.x,B1.y,B1.z,B1.w};
      #pragma unroll
      for (int i = 0; i < 8; ++i)
        #pragma unroll
        for (int j = 0; j < 8; ++j) acc[i][j] += av[i]*bv[j];
    }
  }
  const int tm = m0 + (tid&15)*8;
  const int tn = n0 + (tid>>4)*8;
  #pragma unroll
  for (int i = 0; i < 8; ++i) {
    #pragma unroll
    for (int j = 0; j < 8; ++j) {
      const int n = tn + j;
      P[(size_t)(tm+i)*NGATE + n] = acc[i][j] + bi[n] + bh[n];
    }
  }
}

// ---------------- fused persistent recurrence: PARTIAL-SUM PUSH ----------------
// blocks [0,32): L0 (16 fwd, 16 bwd)   [32,96): L1 (32 fwd, 32 bwd)
// Producer B pushes Y_B[r] = Whh[r, cols_B] . h_B for ALL gate rows r as epoch-tagged
// u64 packets (4 coalesced 4KB bursts). Consumer A polls only its 128(64) rows x sources
// (4 polls/thread), sums, adds P/bias, shuffles gates together, computes h -> pushes.
// The heavy matvec runs BEFORE the inter-block hop; post-arrival tail is ~300 cyc.
__global__ __launch_bounds__(512)
void fused_recur_kernel(const float* __restrict__ Whh0_f, const float* __restrict__ Whh0_b,
                        const float* __restrict__ Wih1_f, const float* __restrict__ Whh1_f,
                        const float* __restrict__ bih1_f, const float* __restrict__ bhh1_f,
                        const float* __restrict__ Wih1_b, const float* __restrict__ Whh1_b,
                        const float* __restrict__ bih1_b, const float* __restrict__ bhh1_b,
                        const float* __restrict__ P_f, const float* __restrict__ P_b,
                        u64* ex0p, u64* ex1p, u64* ex0h,
                        u32* prog0, u32* prog1, float* __restrict__ out)
{
  const int bx   = blockIdx.x;
  const int tid  = threadIdx.x;
  const int wv   = tid >> 6;
  const int lane = tid & 63;

  if (bx < 2*NB0) {
    // ================= layer 0 =================
    const int dir = (bx >= NB0) ? 1 : 0;
    const int A   = bx - dir*NB0;
    const float* Whh = dir ? Whh0_b : Whh0_f;
    const float* P   = dir ? P_b    : P_f;
    u64* exP  = ex0p + (size_t)dir*SLOTS*NB0*NGATE;
    u64* exH  = ex0h + (size_t)dir*SLOTS*HSZ;
    u32* prS  = prog0 + dir*NB0;
    u32* prL1 = prog1 + dir*NB1;

    __shared__ float hb0[2][HB0];

    // consumer map: tid = k*16 + g*4 + sq
    const int k  = tid >> 4;
    const int g  = (tid >> 2) & 3;
    const int sq = tid & 3;
    const int myrow = g*HSZ + A*HB0 + k;
    const bool sq0   = (sq == 0);
    const bool owner = ((tid & 15) == 0);

    // push weights: rows {gg*512 + tid}, cols [A*32, A*32+32)
    float4 wp[4][8];
    #pragma unroll
    for (int gg = 0; gg < 4; ++gg) {
      const float4* src = (const float4*)(Whh + (size_t)(gg*HSZ + tid)*HSZ + A*HB0);
      #pragma unroll
      for (int m = 0; m < 8; ++m) wp[gg][m] = src[m];
    }

    float creg = 0.f;
    float pv = 0.f;
    if (sq0) pv = P[(size_t)(dir ? (T_SEQ-1) : 0)*NGATE + myrow];

    for (int t = 0; t < T_SEQ; ++t) {
      // lazy overwrite guards (issued early, checked pre-barrier)
      u32 pr = 0xFFFFFFFFu;
      if (wv == 1 && lane < NB0)      pr = (u32)pgld(&prS[lane]);
      else if (wv == 2 && lane < NB1) pr = (u32)pgld(&prL1[lane]);
      // P prefetch (one step ahead, register-carried)
      float pvn = 0.f;
      if (sq0) {
        const int tn = (t+1 < T_SEQ) ? t+1 : t;
        const int te = dir ? (T_SEQ-1-tn) : tn;
        pvn = P[(size_t)te*NGATE + myrow];
      }
      // poll 4 partials (epoch t) for my row
      float sum;
      {
        const u64* pb = exP + (size_t)(t & 7)*NB0*NGATE + myrow;
        const u64* q0 = pb + (size_t)(4*sq+0)*NGATE;
        const u64* q1 = pb + (size_t)(4*sq+1)*NGATE;
        const u64* q2 = pb + (size_t)(4*sq+2)*NGATE;
        const u64* q3 = pb + (size_t)(4*sq+3)*NGATE;
        u64 v0=0, v1=0, v2=0, v3=0; u32 pend = 0xFu;
        while (pend) {
          u64 a=0, b=0, c=0, d=0;
          if (pend & 1u) a = exld(q0);
          if (pend & 2u) b = exld(q1);
          if (pend & 4u) c = exld(q2);
          if (pend & 8u) d = exld(q3);
          if ((pend & 1u) && (u32)(a >> 32) == (u32)t) { v0 = a; pend &= ~1u; }
          if ((pend & 2u) && (u32)(b >> 32) == (u32)t) { v1 = b; pend &= ~2u; }
          if ((pend & 4u) && (u32)(c >> 32) == (u32)t) { v2 = c; pend &= ~4u; }
          if ((pend & 8u) && (u32)(d >> 32) == (u32)t) { v3 = d; pend &= ~8u; }
        }
        sum = (__uint_as_float((u32)v0) + __uint_as_float((u32)v1))
            + (__uint_as_float((u32)v2) + __uint_as_float((u32)v3));
      }
      sum += __shfl_xor(sum, 1);
      sum += __shfl_xor(sum, 2);
      if (sq0) sum += pv;
      const float s1 = __shfl_down(sum, 4);
      const float s2 = __shfl_down(sum, 8);
      const float s3 = __shfl_down(sum, 12);
      if (owner) {
        const float i_s = fsigmoid(sum);
        const float f_s = fsigmoid(s1);
        const float g_s = ftanh(s2);
        const float o_s = fsigmoid(s3);
        creg = f_s*creg + i_s*g_s;
        const float hnew = o_s*ftanh(creg);
        hb0[(t+1) & 1][k] = hnew;
        if (t == T_SEQ-1) {
          out[dir*HSZ + A*HB0 + k]        = creg;   // cell_memories L0
          out[2048 + dir*HSZ + A*HB0 + k] = hnew;   // hidden_states L0
        }
      }
      if (wv == 1 && lane < NB0)      { while ((int)pr < t-6) pr = (u32)pgld(&prS[lane]); }
      else if (wv == 2 && lane < NB1) { while ((int)pr < t-6) pr = (u32)pgld(&prL1[lane]); }
      __syncthreads();
      if (tid == 0) pgst(&prS[A], (u32)(t+1));
      // push matvec + coalesced publish (epoch t+1)
      {
        const float4* h4 = (const float4*)hb0[(t+1) & 1];
        const float4 h0 = h4[0], h1 = h4[1], h2 = h4[2], h3 = h4[3];
        const float4 h4v = h4[4], h5 = h4[5], h6 = h4[6], h7 = h4[7];
        u64* dst = exP + (size_t)((t+1) & 7)*NB0*NGATE + (size_t)A*NGATE + tid;
        const u64 tag = (u64)(u32)(t+1) << 32;
        #pragma unroll
        for (int gg = 0; gg < 4; ++gg) {
          const float y = ((dot4(wp[gg][0], h0) + dot4(wp[gg][1], h1))
                        +  (dot4(wp[gg][2], h2) + dot4(wp[gg][3], h3)))
                        + ((dot4(wp[gg][4], h4v) + dot4(wp[gg][5], h5))
                        +  (dot4(wp[gg][6], h6) + dot4(wp[gg][7], h7)));
          exst(dst + (size_t)gg*HSZ, tag | (u64)__float_as_uint(y));
        }
      }
      // publish h itself (for L1's x) as ONE coalesced 256B burst from wave 0
      if (wv == 0 && lane < HB0) {
        const float hv = hb0[(t+1) & 1][lane];
        exst(exH + (size_t)((t+1) & 7)*HSZ + A*HB0 + lane,
             ((u64)(u32)(t+1) << 32) | (u64)__float_as_uint(hv));
      }
      pv = pvn;
    }
  } else {
    // ================= layer 1 =================
    const int r   = bx - 2*NB0;
    const int dir = (r >= NB1) ? 1 : 0;
    const int A   = r - dir*NB1;
    const float* Wih = dir ? Wih1_b : Wih1_f;
    const float* Whh = dir ? Whh1_b : Whh1_f;
    const float* bi  = dir ? bih1_b : bih1_f;
    const float* bh  = dir ? bhh1_b : bhh1_f;
    u64* exP = ex1p + (size_t)dir*SLOTS*NB1*NGATE;
    u64* exX = ex0h + (size_t)dir*SLOTS*HSZ;
    u32* prS = prog1 + dir*NB1;

    __shared__ float xb[2][8*68];    // skewed x chunks (chunk c at c*68)
    __shared__ float hb1[2][HB1];

    // consumer map: tid = k*32 + g*8 + so
    const int k  = tid >> 5;
    const int g  = (tid >> 3) & 3;
    const int so = tid & 7;
    const int myrow = g*HSZ + A*HB1 + k;
    const bool so0   = (so == 0);
    const bool owner = ((tid & 31) == 0);

    // pull weights: Wih[myrow, so*64 .. +64)
    float4 wq[16];
    {
      const float4* src = (const float4*)(Wih + (size_t)myrow*HSZ + so*64);
      #pragma unroll
      for (int m = 0; m < 16; ++m) wq[m] = src[m];
    }
    // push weights: rows {gg*512 + tid}, cols [A*16, A*16+16)
    float4 wp[4][4];
    #pragma unroll
    for (int gg = 0; gg < 4; ++gg) {
      const float4* src = (const float4*)(Whh + (size_t)(gg*HSZ + tid)*HSZ + A*HB1);
      #pragma unroll
      for (int m = 0; m < 4; ++m) wp[gg][m] = src[m];
    }
    float brow = 0.f;
    if (so0) brow = bi[myrow] + bh[myrow];

    float creg = 0.f;
    for (int t = 0; t < T_SEQ; ++t) {
      u32 pr = 0xFFFFFFFFu;
      if (wv == 1 && lane < NB1) pr = (u32)pgld(&prS[lane]);
      // poll x (epoch t+1) + 4 partials (epoch t)
      float xv, sum;
      {
        const u64* qx = exX + (size_t)((t+1) & 7)*HSZ + tid;
        const u64* pb = exP + (size_t)(t & 7)*NB1*NGATE + myrow;
        const u64* q0 = pb + (size_t)(4*so+0)*NGATE;
        const u64* q1 = pb + (size_t)(4*so+1)*NGATE;
        const u64* q2 = pb + (size_t)(4*so+2)*NGATE;
        const u64* q3 = pb + (size_t)(4*so+3)*NGATE;
        u64 vx=0, v0=0, v1=0, v2=0, v3=0; u32 pend = 0x1Fu;
        while (pend) {
          u64 ax=0, a=0, b=0, c=0, d=0;
          if (pend & 16u) ax = exld(qx);
          if (pend & 1u)  a  = exld(q0);
          if (pend & 2u)  b  = exld(q1);
          if (pend & 4u)  c  = exld(q2);
          if (pend & 8u)  d  = exld(q3);
          if ((pend & 16u) && (u32)(ax >> 32) == (u32)(t+1)) { vx = ax; pend &= ~16u; }
          if ((pend & 1u)  && (u32)(a  >> 32) == (u32)t)     { v0 = a;  pend &= ~1u; }
          if ((pend & 2u)  && (u32)(b  >> 32) == (u32)t)     { v1 = b;  pend &= ~2u; }
          if ((pend & 4u)  && (u32)(c  >> 32) == (u32)t)     { v2 = c;  pend &= ~4u; }
          if ((pend & 8u)  && (u32)(d  >> 32) == (u32)t)     { v3 = d;  pend &= ~8u; }
        }
        xv  = __uint_as_float((u32)vx);
        sum = (__uint_as_float((u32)v0) + __uint_as_float((u32)v1))
            + (__uint_as_float((u32)v2) + __uint_as_float((u32)v3));
      }
      xb[t & 1][(tid >> 6)*68 + (tid & 63)] = xv;
      if (wv == 1 && lane < NB1) { while ((int)pr < t-6) pr = (u32)pgld(&prS[lane]); }
      __syncthreads();   // B1: xb[t&1] staged, hb1[t&1] (= h1(t)) stable
      // pull matvec over x chunk `so` + combine with pushed Whh partials
      {
        const float4* x4 = (const float4*)(&xb[t & 1][so*68]);
        float a0 = 0.f, a1 = 0.f;
        #pragma unroll
        for (int m = 0; m < 16; m += 2) {
          a0 += dot4(wq[m],   x4[m]);
          a1 += dot4(wq[m+1], x4[m+1]);
        }
        sum += a0 + a1;
      }
      sum += __shfl_xor(sum, 1);
      sum += __shfl_xor(sum, 2);
      sum += __shfl_xor(sum, 4);
      if (so0) sum += brow;
      const float s1 = __shfl_down(sum, 8);
      const float s2 = __shfl_down(sum, 16);
      const float s3 = __shfl_down(sum, 24);
      if (owner) {
        const float i_s = fsigmoid(sum);
        const float f_s = fsigmoid(s1);
        const float g_s = ftanh(s2);
        const float o_s = fsigmoid(s3);
        creg = f_s*creg + i_s*g_s;
        const float hnew = o_s*ftanh(creg);
        hb1[(t+1) & 1][k] = hnew;
        if (t == T_SEQ-1) {
          out[1024 + dir*HSZ + A*HB1 + k] = creg;   // cell_memories L1
          out[3072 + dir*HSZ + A*HB1 + k] = hnew;   // hidden_states L1
        }
      }
      __syncthreads();   // B2: hb1[(t+1)&1] ready
      if (tid == 0) pgst(&prS[A], (u32)(t+1));
      // push matvec + coalesced publish (epoch t+1)
      {
        const float4* h4 = (const float4*)hb1[(t+1) & 1];
        const float4 h0 = h4[0], h1 = h4[1], h2 = h4[2], h3 = h4[3];
        u64* dst = exP + (size_t)((t+1) & 7)*NB1*NGATE + (size_t)A*NGATE + tid;
        const u64 tag = (u64)(u32)(t+1) << 32;
        #pragma unroll
        for (int gg = 0; gg < 4; ++gg) {
          const float y = (dot4(wp[gg][0], h0) + dot4(wp[gg][1], h1))
                        + (dot4(wp[gg][2], h2) + dot4(wp[gg][3], h3));
          exst(dst + (size_t)gg*HSZ, tag | (u64)__float_as_uint(y));
        }
      }
      // top-layer output: ONE exact 64B line from wave 0
      if (wv == 0 && lane < 4) {
        const float4 v = *(const float4*)(&hb1[(t+1) & 1][lane*4]);
        const int trow = dir ? (T_SEQ-1-t) : t;
        *(float4*)(out + 4096 + (size_t)trow*1024 + dir*HSZ + A*HB1 + lane*4) = v;
      }
    }
  }
}

// ---------------- launch ----------------
extern "C" void kernel_launch(void* const* d_in, const int* in_sizes, int n_in,
                              void* d_out, int out_size, void* d_ws, size_t ws_size,
                              hipStream_t stream)
{
  const float* emb   = (const float*)d_in[0];
  const float* fWih0 = (const float*)d_in[1];
  const float* fWhh0 = (const float*)d_in[2];
  const float* fbih0 = (const float*)d_in[3];
  const float* fbhh0 = (const float*)d_in[4];
  const float* fWih1 = (const float*)d_in[5];
  const float* fWhh1 = (const float*)d_in[6];
  const float* fbih1 = (const float*)d_in[7];
  const float* fbhh1 = (const float*)d_in[8];
  const float* bWih0 = (const float*)d_in[9];
  const float* bWhh0 = (const float*)d_in[10];
  const float* bbih0 = (const float*)d_in[11];
  const float* bbhh0 = (const float*)d_in[12];
  const float* bWih1 = (const float*)d_in[13];
  const float* bWhh1 = (const float*)d_in[14];
  const float* bbih1 = (const float*)d_in[15];
  const float* bbhh1 = (const float*)d_in[16];
  float* out = (float*)d_out;

  // ws: P[2][4096][2048] fp32 (64MB), ex0p 4MB, ex1p 8MB, ex0h 64KB, prog flags
  float* P_f  = (float*)d_ws;
  float* P_b  = P_f + (size_t)T_SEQ*NGATE;
  u64*   ex0p = (u64*)(P_b + (size_t)T_SEQ*NGATE);
  u64*   ex1p = ex0p + (size_t)2*SLOTS*NB0*NGATE;
  u64*   ex0h = ex1p + (size_t)2*SLOTS*NB1*NGATE;
  u32*   prog0 = (u32*)(ex0h + (size_t)2*SLOTS*HSZ);
  u32*   prog1 = prog0 + 2*NB0;

  init_sync_kernel<<<128, 1024, 0, stream>>>(ex0p, prog0);

  gemm_bias_kernel<<<dim3(32,16,2), 256, 0, stream>>>(
      emb, emb, fWih0, bWih0, fbih0, fbhh0, bbih0, bbhh0, P_f, P_b, DIN);

  fused_recur_kernel<<<96, 512, 0, stream>>>(
      fWhh0, bWhh0,
      fWih1, fWhh1, fbih1, fbhh1,
      bWih1, bWhh1, bbih1, bbhh1,
      P_f, P_b, ex0p, ex1p, ex0h, prog0, prog1, out);
}